// Round 8
// baseline (63.416 us; speedup 1.0000x reference)
//
#include <hip/hip_runtime.h>
#include <hip/hip_bf16.h>

typedef __attribute__((ext_vector_type(8))) short short8;
typedef __attribute__((ext_vector_type(4))) float f32x4;
typedef __attribute__((ext_vector_type(16))) float f32x16;

#define NROWS 65536             // BATCH * N_EDGES
#define EDGE_DIM 64
#define NODE_DIM 32
#define NN 1024                 // NODE_DIM^2

__device__ __forceinline__ short f2bf(float f) {
    unsigned u = __builtin_bit_cast(unsigned, f);
    u += 0x7FFFu + ((u >> 16) & 1u);            // round-to-nearest-even
    return (short)(u >> 16);
}

// Single fused kernel. 512 blocks x 512 threads (8 waves) x 128 edges/block.
// Wave wid owns output rows i = wid*4 .. wid*4+3: their 16 W fragments are
// loaded ONCE from f32 W (coalesced column reads, L2/L3-hot) into 64 VGPRs —
// no prep kernel, no W in LDS. Block stages only the edge bf16 fragments in
// LDS (16 KB -> 2 blocks/CU, 4 waves/SIMD). Per edge-group (32 edges):
// 4 ds_read_b128 (ef) + 4 dwordx4 (node) + per-i {bias C-init, 4-chain
// mfma_32x32x16, relu+matvec epilogue (4 indep partials), shfl_xor(32)},
// then one coalesced f32x4 store per lane<32.
__global__ __launch_bounds__(512, 4) void mp_fused(
    const float* __restrict__ node, const float* __restrict__ edge,
    const float* __restrict__ W, const float* __restrict__ bias,
    float* __restrict__ out) {
    // ldsE[eg][ks][lane][8 shorts]: 4*4*64*8 = 8192 shorts = 16 KB
    __shared__ __align__(16) short ldsE[8192];

    const int tid = threadIdx.x;
    const int wid = tid >> 6;                 // 0..7 -> i-quad
    const int l   = tid & 63;
    const int e32 = l & 31;                   // lane's edge col (MFMA N)
    const int h   = l >> 5;                   // lane half (k-group / row offset)
    const int eb  = blockIdx.x * 128;         // block's first edge row

    // ---- W fragments for this wave's 4 i's -> registers (one-time) ----
    // wfr[il][ks][t] = bf16(W[ks*16 + h*8 + t, (wid*4+il)*32 + e32])
    short8 wfr[4][4];
#pragma unroll
    for (int il = 0; il < 4; ++il)
#pragma unroll
        for (int ks = 0; ks < 4; ++ks) {
            const float* wp = W + (size_t)(ks * 16 + h * 8) * NN
                                + (wid * 4 + il) * 32 + e32;
            short8 v;
#pragma unroll
            for (int t = 0; t < 8; ++t)
                v[t] = f2bf(wp[(size_t)t * NN]);
            wfr[il][ks] = v;
        }

    // ---- stage edge fragments: 1024 16B-entries, 2 per thread ----
#pragma unroll
    for (int k = 0; k < 2; ++k) {
        int n = k * 512 + tid;                // entry id
        int le = n & 63;                      // entry lane
        int ks = (n >> 6) & 3;
        int eg = n >> 8;
        const float* erow = edge + (size_t)(eb + eg * 32 + (le & 31)) * EDGE_DIM
                                 + ks * 16 + (le >> 5) * 8;
        f32x4 a = *reinterpret_cast<const f32x4*>(erow);
        f32x4 b = *reinterpret_cast<const f32x4*>(erow + 4);
        short8 v;
        v[0] = f2bf(a[0]); v[1] = f2bf(a[1]); v[2] = f2bf(a[2]); v[3] = f2bf(a[3]);
        v[4] = f2bf(b[0]); v[5] = f2bf(b[1]); v[6] = f2bf(b[2]); v[7] = f2bf(b[3]);
        *reinterpret_cast<short8*>(&ldsE[n * 8]) = v;
    }
    __syncthreads();                          // the ONLY barrier

#pragma unroll
    for (int eg = 0; eg < 4; ++eg) {
        // edge B-fragments for this 32-edge group
        short8 ef0 = *reinterpret_cast<const short8*>(&ldsE[((eg * 4 + 0) * 64 + l) * 8]);
        short8 ef1 = *reinterpret_cast<const short8*>(&ldsE[((eg * 4 + 1) * 64 + l) * 8]);
        short8 ef2 = *reinterpret_cast<const short8*>(&ldsE[((eg * 4 + 2) * 64 + l) * 8]);
        short8 ef3 = *reinterpret_cast<const short8*>(&ldsE[((eg * 4 + 3) * 64 + l) * 8]);

        // node values: acc reg r=q*4+rr -> j = q*8 + h*4 + rr
        const float* nrow = node + (size_t)(eb + eg * 32 + e32) * NODE_DIM;
        f32x4 n0 = *reinterpret_cast<const f32x4*>(nrow + 0 * 8 + h * 4);
        f32x4 n1 = *reinterpret_cast<const f32x4*>(nrow + 1 * 8 + h * 4);
        f32x4 n2 = *reinterpret_cast<const f32x4*>(nrow + 2 * 8 + h * 4);
        f32x4 n3 = *reinterpret_cast<const f32x4*>(nrow + 3 * 8 + h * 4);

        f32x4 vq;
#pragma unroll
        for (int il = 0; il < 4; ++il) {
            const int i = wid * 4 + il;
            // bias as C-init: reg q*4+rr -> row q*8 + h*4 + rr (L1-hot, 4 KB)
            f32x16 acc;
#pragma unroll
            for (int q = 0; q < 4; ++q) {
                f32x4 bq = *reinterpret_cast<const f32x4*>(bias + i * 32 + q * 8 + h * 4);
                acc[q * 4 + 0] = bq[0]; acc[q * 4 + 1] = bq[1];
                acc[q * 4 + 2] = bq[2]; acc[q * 4 + 3] = bq[3];
            }
            acc = __builtin_amdgcn_mfma_f32_32x32x16_bf16(wfr[il][0], ef0, acc, 0, 0, 0);
            acc = __builtin_amdgcn_mfma_f32_32x32x16_bf16(wfr[il][1], ef1, acc, 0, 0, 0);
            acc = __builtin_amdgcn_mfma_f32_32x32x16_bf16(wfr[il][2], ef2, acc, 0, 0, 0);
            acc = __builtin_amdgcn_mfma_f32_32x32x16_bf16(wfr[il][3], ef3, acc, 0, 0, 0);

            // relu + matvec, 4 independent partials (chain depth 4)
            float s0 = 0.f, s1 = 0.f, s2 = 0.f, s3 = 0.f;
#pragma unroll
            for (int rr = 0; rr < 4; ++rr) {
                s0 += fmaxf(acc[rr],      0.f) * n0[rr];
                s1 += fmaxf(acc[4 + rr],  0.f) * n1[rr];
                s2 += fmaxf(acc[8 + rr],  0.f) * n2[rr];
                s3 += fmaxf(acc[12 + rr], 0.f) * n3[rr];
            }
            float p = (s0 + s1) + (s2 + s3);
            p += __shfl_xor(p, 32);           // add partner half's 16 j's
            vq[il] = p;
        }
        // store msg[eb+eg*32+l, wid*4 .. wid*4+3] (16B per lane<32)
        if (l < 32)
            *reinterpret_cast<f32x4*>(out + (size_t)(eb + eg * 32 + l) * NODE_DIM
                                      + wid * 4) = vq;
    }
}

extern "C" void kernel_launch(void* const* d_in, const int* in_sizes, int n_in,
                              void* d_out, int out_size, void* d_ws, size_t ws_size,
                              hipStream_t stream) {
    const float* node = (const float*)d_in[0];  // [16,4096,32] f32
    const float* edge = (const float*)d_in[1];  // [16,4096,64] f32
    const float* W    = (const float*)d_in[2];  // [64,1024] f32
    const float* bias = (const float*)d_in[3];  // [1024] f32
    float* out = (float*)d_out;                 // [16,4096,32] f32

    mp_fused<<<dim3(NROWS / 128), dim3(512), 0, stream>>>(node, edge, W, bias, out);
}

// Round 9
// 29.893 us; speedup vs baseline: 2.1215x; 2.1215x over previous
//
#include <hip/hip_runtime.h>
#include <hip/hip_bf16.h>

typedef __attribute__((ext_vector_type(8))) short short8;
typedef __attribute__((ext_vector_type(4))) float f32x4;
typedef __attribute__((ext_vector_type(16))) float f32x16;
typedef unsigned int u32;

#define NROWS 65536             // BATCH * N_EDGES
#define EDGE_DIM 64
#define NODE_DIM 32
#define NN 1024                 // NODE_DIM^2

__device__ __forceinline__ short f2bf(float f) {
    unsigned u = __builtin_bit_cast(unsigned, f);
    u += 0x7FFFu + ((u >> 16) & 1u);            // round-to-nearest-even
    return (short)(u >> 16);
}

// async 16B global->LDS copy (dest = wave-uniform base + lane*16)
__device__ __forceinline__ void gload_lds16(const void* g, void* l) {
    __builtin_amdgcn_global_load_lds(
        (const __attribute__((address_space(1))) u32*)g,
        (__attribute__((address_space(3))) u32*)l, 16, 0, 0);
}

// Pack W [64,1024] f32 -> bf16 A-operand fragments for mfma_f32_32x32x16_bf16.
// frag id = i*4 + ks (i = output row 0..31, ks = K-step 0..3).
// Wb[(frag*64 + l)*8 + t] = bf16(W[ks*16 + (l>>5)*8 + t, i*32 + (l&31)])
// (verified correct R2/R3/R5/R6/R7)
__global__ void prep_W(const float* __restrict__ W, short* __restrict__ Wb) {
    int frag = blockIdx.x;            // 128 blocks x 1 wave
    int l = threadIdx.x;              // 0..63
    int col = (frag >> 2) * 32 + (l & 31);
    int fb = (frag & 3) * 16 + ((l >> 5) * 8);
    short8 v;
#pragma unroll
    for (int t = 0; t < 8; ++t)
        v[t] = f2bf(W[(size_t)(fb + t) * NN + col]);
    *reinterpret_cast<short8*>(Wb + ((size_t)frag * 64 + l) * 8) = v;
}

// 512 blocks x 512 threads (8 waves x 32 edges = 256 edges/block), i-dim
// split in half across block pairs: each block stages 16 i's of packed W
// (64 KB, contiguous in Wb) via global_load_lds -> 2 blocks/CU, 4 waves/SIMD
// (launch_bounds(512,2): 128-VGPR cap under blocks/CU semantics — R8's
// (512,4) forced 64 VGPR and spilled to scratch, FETCH/WRITE ~100 MB).
// bid = g*16 + ihalf*8 + xcd: the two i-half blocks sharing an edge chunk
// land on the same XCD, so the 2nd edge read is L2-hot. One barrier; then
// barrier-free i-loop: 4 conflict-free ds_read_b128 + bias C-init (L1-hot)
// + 4-chain mfma_32x32x16 + relu/matvec epilogue (4 indep partials) +
// shfl_xor(32) + direct f32x4 stores from lanes<32.
__global__ __launch_bounds__(512, 2) void mp_main(
    const float* __restrict__ node, const float* __restrict__ edge,
    const short* __restrict__ Wb, const float* __restrict__ bias,
    float* __restrict__ out) {
    __shared__ __align__(16) short ldsW[32768];   // 64 KB: 16 i's of packed W

    const int tid = threadIdx.x;
    const int wid = tid >> 6;                 // 0..7
    const int l   = tid & 63;
    const int e32 = l & 31;                   // lane's edge col (MFMA N)
    const int h   = l >> 5;                   // lane half (k-group / row offset)

    const int bid    = blockIdx.x;            // = g*16 + ihalf*8 + xcd
    const int g      = bid >> 4;
    const int ihalf  = (bid >> 3) & 1;
    const int xcd    = bid & 7;
    const int echunk = g * 8 + xcd;           // 0..255
    const int ibase  = ihalf * 16;
    const int eb     = echunk * 256 + wid * 32;
    const int e      = eb + e32;

    // ---- per-lane inputs (issued before staging; barrier drains all) ----
    // ef[ks]: k = h*8+t -> edge[e, ks*16 + h*8 + t]
    // nv[q*4+rr]: acc reg r=q*4+rr -> j = q*8 + h*4 + rr
    short8 ef[4];
    float  nv[16];
    const float* erow = edge + (size_t)e * EDGE_DIM;
#pragma unroll
    for (int ks = 0; ks < 4; ++ks) {
        f32x4 a = *reinterpret_cast<const f32x4*>(erow + ks * 16 + h * 8);
        f32x4 b = *reinterpret_cast<const f32x4*>(erow + ks * 16 + h * 8 + 4);
        short8 v;
        v[0] = f2bf(a[0]); v[1] = f2bf(a[1]); v[2] = f2bf(a[2]); v[3] = f2bf(a[3]);
        v[4] = f2bf(b[0]); v[5] = f2bf(b[1]); v[6] = f2bf(b[2]); v[7] = f2bf(b[3]);
        ef[ks] = v;
    }
    const float* nrow = node + (size_t)e * NODE_DIM;
#pragma unroll
    for (int q = 0; q < 4; ++q) {
        f32x4 n = *reinterpret_cast<const f32x4*>(nrow + q * 8 + h * 4);
        nv[q * 4 + 0] = n[0]; nv[q * 4 + 1] = n[1];
        nv[q * 4 + 2] = n[2]; nv[q * 4 + 3] = n[3];
    }

    // ---- stage this i-half's W: 8 x (512 lanes x 16 B) = 64 KB ----
    const short* wsrc = Wb + (size_t)ibase * 2048;   // frags [ibase*4, +64)
#pragma unroll
    for (int k = 0; k < 8; ++k)
        gload_lds16(wsrc + (size_t)(k * 512 + tid) * 8,
                    &ldsW[(size_t)k * 4096 + wid * 512]);
    __syncthreads();                          // the ONLY barrier

    float* orow = out + (size_t)(eb + (l & 31)) * NODE_DIM + ibase;

#pragma unroll 2
    for (int iq = 0; iq < 4; ++iq) {
        f32x4 vq;
#pragma unroll
        for (int r = 0; r < 4; ++r) {
            const int il = iq * 4 + r;        // 0..15 (local i)
            const short* wp = &ldsW[(size_t)il * 2048 + l * 8];
            short8 w0 = *reinterpret_cast<const short8*>(wp + 0 * 512);
            short8 w1 = *reinterpret_cast<const short8*>(wp + 1 * 512);
            short8 w2 = *reinterpret_cast<const short8*>(wp + 2 * 512);
            short8 w3 = *reinterpret_cast<const short8*>(wp + 3 * 512);

            // bias as C-init: reg q*4+rr -> row q*8 + h*4 + rr (L1-hot)
            const int i = ibase + il;
            f32x16 acc;
#pragma unroll
            for (int q = 0; q < 4; ++q) {
                f32x4 bq = *reinterpret_cast<const f32x4*>(bias + i * 32 + q * 8 + h * 4);
                acc[q * 4 + 0] = bq[0]; acc[q * 4 + 1] = bq[1];
                acc[q * 4 + 2] = bq[2]; acc[q * 4 + 3] = bq[3];
            }

            acc = __builtin_amdgcn_mfma_f32_32x32x16_bf16(w0, ef[0], acc, 0, 0, 0);
            acc = __builtin_amdgcn_mfma_f32_32x32x16_bf16(w1, ef[1], acc, 0, 0, 0);
            acc = __builtin_amdgcn_mfma_f32_32x32x16_bf16(w2, ef[2], acc, 0, 0, 0);
            acc = __builtin_amdgcn_mfma_f32_32x32x16_bf16(w3, ef[3], acc, 0, 0, 0);

            // relu + matvec, 4 independent partials (chain depth 4)
            float s0 = 0.f, s1 = 0.f, s2 = 0.f, s3 = 0.f;
#pragma unroll
            for (int rr = 0; rr < 4; ++rr) {
                s0 += fmaxf(acc[rr],      0.f) * nv[rr];
                s1 += fmaxf(acc[4 + rr],  0.f) * nv[4 + rr];
                s2 += fmaxf(acc[8 + rr],  0.f) * nv[8 + rr];
                s3 += fmaxf(acc[12 + rr], 0.f) * nv[12 + rr];
            }
            float p = (s0 + s1) + (s2 + s3);
            p += __shfl_xor(p, 32);           // add partner half's 16 j's
            vq[r] = p;
        }
        if (l < 32)
            *reinterpret_cast<f32x4*>(orow + iq * 4) = vq;  // msg[e, ibase+iq*4..]
    }
}

extern "C" void kernel_launch(void* const* d_in, const int* in_sizes, int n_in,
                              void* d_out, int out_size, void* d_ws, size_t ws_size,
                              hipStream_t stream) {
    const float* node = (const float*)d_in[0];  // [16,4096,32] f32
    const float* edge = (const float*)d_in[1];  // [16,4096,64] f32
    const float* W    = (const float*)d_in[2];  // [64,1024] f32
    const float* bias = (const float*)d_in[3];  // [1024] f32
    float* out = (float*)d_out;                 // [16,4096,32] f32
    short* Wb = (short*)d_ws;                   // 128 KB bf16 fragment-packed W

    prep_W<<<dim3(128), dim3(64), 0, stream>>>(W, Wb);
    mp_main<<<dim3(512), dim3(512), 0, stream>>>(node, edge, Wb, bias, out);
}